// Round 7
// baseline (112.406 us; speedup 1.0000x reference)
//
#include <hip/hip_runtime.h>

// Problem constants: x [B=1,T=8,C=32,D=32,H=64,W=64] fp32
constexpr int NT = 8;    // B*T
constexpr int C  = 32;
constexpr int D  = 32;
constexpr int H  = 64;
constexpr int W  = 64;   // == wavefront size: W-conv via lane shuffles
constexpr int ROWS = 4;  // h rows per block (one per wave)
constexpr int SP = D * H * W;       // per-channel spatial size = 131072
constexpr int HW = H * W;           // d-plane stride = 4096 elements (16384 B)

typedef unsigned int u32;
typedef u32 u32x4 __attribute__((ext_vector_type(4)));

// Buffer resource descriptor (SRD) for raw dword access; bounds check off.
static __device__ __forceinline__ u32x4 make_srd(const float* p) {
    u32x4 s;
    s.x = (u32)(unsigned long long)p;
    s.y = (u32)(((unsigned long long)p) >> 32);
    s.z = 0xFFFFFFFFu;      // num_records: disable bounds check
    s.w = 0x00020000u;      // raw untyped dword
    return s;
}

// ---------------------------------------------------------------------------
// Kernel A: fused depthwise chain, LDS-free.
//   h = zconv3(x)+bz ; h = hconv3(h)+bx ; h = wconv3(h)+by ; 3x: h = zconv5_dil2(h)+bs
// One wave per (n,c,h) row; lane = w; thread owns the full D=32 column in regs.
//
// Round-7 fix: the 96 input loads are HAND-ISSUED as asm volatile
// buffer_load_dword (3 row-base SRDs, voffset = w*4, soffset = d*16384
// compile-time const per unrolled iter). Volatile asm preserves program
// order and forces real register destinations -> ~60 loads in flight per
// wave (vmcnt queue depth) instead of the ~3 the compiler's register-
// pressure heuristic allowed. One s_waitcnt vmcnt(0) + sched_barrier(0)
// separates the batch from the (unchanged, proven) compute.
//
// Boundary bias semantics: a later conv's out-of-image tap drops its whole
// term (incl. earlier biases) — clamped row address + zeroed tap weight
// (term enters as wxk*(zconv+bz), so wxk=0 is exact).
// ---------------------------------------------------------------------------
__global__ __launch_bounds__(256, 3)
void dw_chain(const float* __restrict__ x,
              const float* __restrict__ w0z, const float* __restrict__ b0z,
              const float* __restrict__ w0x, const float* __restrict__ b0x,
              const float* __restrict__ w0y, const float* __restrict__ b0y,
              const float* __restrict__ wsz, const float* __restrict__ bsz,
              float* __restrict__ hdw)
{
    // XCD-chunk swizzle: 4096 blocks, 8 XCDs, chunk = 512 => XCD k owns one n
    // entirely: halo-row re-reads stay in that XCD's L2.
    const int rr  = blockIdx.x;
    const int lid = (rr & 7) * (NT * C * (H / ROWS) / 8) + (rr >> 3);
    const int htile = lid % (H / ROWS);
    const int c     = (lid / (H / ROWS)) % C;
    const int n     = lid / ((H / ROWS) * C);

    const int tid = threadIdx.x;
    const int w   = tid & 63;                              // lane (divergent)
    // wave-uniform h row, forced into an SGPR:
    const int hg  = __builtin_amdgcn_readfirstlane(htile * ROWS + (tid >> 6));

    const float* xc = x + ((size_t)n * C + c) * SP;

    // Per-channel weights (block-uniform -> scalar regs)
    const float wz0 = w0z[c*3+0], wz1 = w0z[c*3+1], wz2 = w0z[c*3+2];
    const float wx1 = w0x[c*3+1];
    const float wy0 = w0y[c*3+0], wy1 = w0y[c*3+1], wy2 = w0y[c*3+2];
    const float bz = b0z[c], bx = b0x[c], by = b0y[c], bs = bsz[c];
    float wsk[5];
    #pragma unroll
    for (int k = 0; k < 5; ++k) wsk[k] = wsz[c*5+k];

    // Boundary: clamp row index (legal load), zero the tap weight (exact).
    const float wxk0 = (hg > 0)     ? w0x[c*3+0] : 0.f;
    const float wxk2 = (hg < H - 1) ? w0x[c*3+2] : 0.f;
    const int   hm = (hg > 0)     ? hg - 1 : 0;
    const int   hp = (hg < H - 1) ? hg + 1 : H - 1;

    // One SRD per h-row (wave-uniform base -> SALU); soffset selects d-plane.
    const u32x4 s0 = make_srd(xc + (size_t)hm * W);
    const u32x4 s1 = make_srd(xc + (size_t)hg * W);
    const u32x4 s2 = make_srd(xc + (size_t)hp * W);
    const u32 voff = (u32)(w * 4);

    // ---- Hand-issued batch of ALL 96 loads -------------------------------
    float a0[D], a1[D], a2[D];
    #pragma unroll
    for (int d = 0; d < D; ++d) {
        const u32 so = (u32)(d * HW * 4);   // compile-time const per iter
        asm volatile("buffer_load_dword %0, %1, %2, %3 offen"
                     : "=v"(a0[d]) : "v"(voff), "s"(s0), "s"(so));
        asm volatile("buffer_load_dword %0, %1, %2, %3 offen"
                     : "=v"(a1[d]) : "v"(voff), "s"(s1), "s"(so));
        asm volatile("buffer_load_dword %0, %1, %2, %3 offen"
                     : "=v"(a2[d]) : "v"(voff), "s"(s2), "s"(so));
    }
    asm volatile("s_waitcnt vmcnt(0)" ::: "memory");
    __builtin_amdgcn_sched_barrier(0);   // nothing crosses the wait (rule #18)

    // ---- h-conv (along H): hrow = wxk0*r0 + wx1*r1 + wxk2*r2 ------------
    float hrow[D];
    #pragma unroll
    for (int d = 0; d < D; ++d)
        hrow[d] = wxk0 * a0[d] + wx1 * a1[d] + wxk2 * a2[d];

    // ---- z-conv (along D) + folded biases --------------------------------
    const float cb = bx + (wxk0 + wx1 + wxk2) * bz;
    float acc2[D];
    #pragma unroll
    for (int d = 0; d < D; ++d) {
        float t = cb + wz1 * hrow[d];
        if (d > 0)     t += wz0 * hrow[d - 1];
        if (d < D - 1) t += wz2 * hrow[d + 1];
        acc2[d] = t;
    }

    // ---- w-conv via lane shuffles (W == 64 == wavefront) -----------------
    const bool has_l = (w > 0), has_r = (w < W - 1);
    float acc3[D];
    #pragma unroll
    for (int d = 0; d < D; ++d) {
        float left  = __shfl_up(acc2[d], 1);
        float right = __shfl_down(acc2[d], 1);
        float t = by + wy1 * acc2[d];
        if (has_l) t += wy0 * left;
        if (has_r) t += wy2 * right;
        acc3[d] = t;
    }

    // ---- three 5-tap dilation-2 convs along D (pad 4), in registers ------
    #pragma unroll
    for (int it = 0; it < 3; ++it) {
        float s[D];
        #pragma unroll
        for (int d = 0; d < D; ++d) {
            float t = bs;
            #pragma unroll
            for (int k = 0; k < 5; ++k) {
                int j = d + 2 * k - 4;
                if (j >= 0 && j < D) t += wsk[k] * acc3[j];
            }
            s[d] = t;
        }
        #pragma unroll
        for (int d = 0; d < D; ++d) acc3[d] = s[d];
    }

    // ---- store column: scalar base + w (coalesced across lanes) ----------
    float* oc = hdw + ((size_t)n * C + c) * SP + (size_t)hg * W;
    #pragma unroll
    for (int d = 0; d < D; ++d) oc[(size_t)d * HW + w] = acc3[d];
}

// ---------------------------------------------------------------------------
// Kernel B: pointwise 1x1x1 conv over channels + residual multiply, IN PLACE
// on io (= d_out holding the depthwise-chain result). Near mixed L3/HBM
// roofline — unchanged.
// ---------------------------------------------------------------------------
__global__ __launch_bounds__(256)
void pw_mul(const float* __restrict__ x,
            const float* __restrict__ wp, const float* __restrict__ bp,
            float* __restrict__ io)
{
    const size_t p = (size_t)blockIdx.x * 256 + threadIdx.x;  // (n, d, h, w)
    const size_t n  = p / SP;
    const size_t sp = p % SP;
    const size_t base = n * (size_t)C * SP + sp;

    float v[C];
    #pragma unroll
    for (int ci = 0; ci < C; ++ci) v[ci] = io[base + (size_t)ci * SP];

    for (int co = 0; co < C; ++co) {
        float y = bp[co];
        #pragma unroll
        for (int ci = 0; ci < C; ++ci) y += wp[co * C + ci] * v[ci];
        const size_t idx = base + (size_t)co * SP;
        io[idx] = x[idx] * y;
    }
}

extern "C" void kernel_launch(void* const* d_in, const int* in_sizes, int n_in,
                              void* d_out, int out_size, void* d_ws, size_t ws_size,
                              hipStream_t stream)
{
    const float* x   = (const float*)d_in[0];
    const float* w0z = (const float*)d_in[1];
    const float* b0z = (const float*)d_in[2];
    const float* w0x = (const float*)d_in[3];
    const float* b0x = (const float*)d_in[4];
    const float* w0y = (const float*)d_in[5];
    const float* b0y = (const float*)d_in[6];
    const float* wsz = (const float*)d_in[7];
    const float* bsz = (const float*)d_in[8];
    const float* wp  = (const float*)d_in[9];
    const float* bp  = (const float*)d_in[10];
    float* out = (float*)d_out;

    // Kernel A: depthwise chain -> d_out (scratch)
    const int gridA = NT * C * (H / ROWS);        // 4096 blocks, 256 thr
    dw_chain<<<gridA, 256, 0, stream>>>(x, w0z, b0z, w0x, b0x, w0y, b0y,
                                        wsz, bsz, out);

    // Kernel B: pointwise + residual, in place on d_out
    const int positions = NT * SP;                // 1,048,576
    pw_mul<<<positions / 256, 256, 0, stream>>>(x, wp, bp, out);
}